// Round 1
// baseline (357.853 us; speedup 1.0000x reference)
//
#include <hip/hip_runtime.h>

// Problem constants (from reference: BATCH=64, NUM_SPEC=8, VOCAB=128000)
constexpr int BATCH    = 64;
constexpr int NUM_SPEC = 8;
constexpr int VOCAB    = 128000;
constexpr int ROWS     = BATCH * NUM_SPEC;   // 512 argmax rows
constexpr int NVEC     = VOCAB / 4;          // 32000 float4 per row
constexpr int T1       = 512;                // threads per argmax block

// Kernel 1: per-row argmax over vocab (first-index tie-break, matching jnp.argmax).
// One block per (batch, spec) row. float4 coalesced loads, wave shuffle reduce,
// LDS cross-wave reduce.
__global__ __launch_bounds__(T1) void rs_argmax(const float* __restrict__ logits,
                                                int* __restrict__ targets) {
    const int row = blockIdx.x;  // 0..511
    const float4* __restrict__ rowp =
        reinterpret_cast<const float4*>(logits + (size_t)row * VOCAB);

    float best = -__builtin_inff();
    int   bidx = VOCAB;  // sentinel > any real index

    // Per-thread indices are strictly increasing, so '>' alone keeps the
    // first (lowest) index on exact ties within a thread.
    for (int i = threadIdx.x; i < NVEC; i += T1) {
        const float4 v = rowp[i];
        const int base = i << 2;
        if (v.x > best) { best = v.x; bidx = base;     }
        if (v.y > best) { best = v.y; bidx = base + 1; }
        if (v.z > best) { best = v.z; bidx = base + 2; }
        if (v.w > best) { best = v.w; bidx = base + 3; }
    }

    // 64-lane wave reduction with lowest-index tie-break.
    #pragma unroll
    for (int off = 32; off > 0; off >>= 1) {
        const float ov = __shfl_down(best, off, 64);
        const int   oi = __shfl_down(bidx, off, 64);
        if (ov > best || (ov == best && oi < bidx)) { best = ov; bidx = oi; }
    }

    __shared__ float sval[T1 / 64];
    __shared__ int   sidx[T1 / 64];
    const int lane = threadIdx.x & 63;
    const int wave = threadIdx.x >> 6;
    if (lane == 0) { sval[wave] = best; sidx[wave] = bidx; }
    __syncthreads();

    if (threadIdx.x == 0) {
        best = sval[0]; bidx = sidx[0];
        #pragma unroll
        for (int w = 1; w < T1 / 64; ++w) {
            if (sval[w] > best || (sval[w] == best && sidx[w] < bidx)) {
                best = sval[w]; bidx = sidx[w];
            }
        }
        targets[row] = bidx;
    }
}

// Kernel 2: per-batch rejection-sampling logic. One thread per batch row.
// Output layout (all int32, concatenated flat in return order):
//   [0,          576)  output_token_ids [64,9]
//   [576,        640)  num_rejected_tokens [64]
//   [640,        704)  last_token_ids [64]
__global__ __launch_bounds__(64) void rs_finalize(const int* __restrict__ targets,
                                                  const int* __restrict__ draft,
                                                  const int* __restrict__ bonus,
                                                  int* __restrict__ out) {
    const int b = threadIdx.x;
    if (b >= BATCH) return;

    int tgt[NUM_SPEC];
    int L = 0;            // matched-prefix length
    bool prefix = true;
    #pragma unroll
    for (int s = 0; s < NUM_SPEC; ++s) {
        tgt[s] = targets[b * NUM_SPEC + s];
        const bool m = (draft[b * NUM_SPEC + s] == tgt[s]);
        prefix = prefix && m;
        if (prefix) ++L;
    }

    const bool all_acc = (L == NUM_SPEC);
    // keeps[s] = (s <= first_diff) | equals[s]  ==>  first (L+1) positions kept
    // when L<8 (the correction token at position L), all 8 kept when L==8.
    const int keep_cnt = all_acc ? NUM_SPEC : (L + 1);

    int* __restrict__ out_tok = out + b * (NUM_SPEC + 1);
    #pragma unroll
    for (int s = 0; s < NUM_SPEC; ++s) {
        out_tok[s] = (s < keep_cnt) ? tgt[s] : -1;
    }
    const int bonus_tok = bonus[b];
    out_tok[NUM_SPEC] = all_acc ? bonus_tok : -1;

    out[BATCH * (NUM_SPEC + 1) + b] = NUM_SPEC - L;                    // num_rejected
    out[BATCH * (NUM_SPEC + 1) + BATCH + b] = all_acc ? bonus_tok      // last_token
                                                      : tgt[L];
}

extern "C" void kernel_launch(void* const* d_in, const int* in_sizes, int n_in,
                              void* d_out, int out_size, void* d_ws, size_t ws_size,
                              hipStream_t stream) {
    const float* logits = (const float*)d_in[0];  // [64, 8, 128000] fp32
    const int*   draft  = (const int*)d_in[1];    // [64, 8] int32
    const int*   bonus  = (const int*)d_in[2];    // [64, 1] int32
    int* out = (int*)d_out;                       // 704 int32
    int* targets = (int*)d_ws;                    // 512 int32 scratch

    rs_argmax<<<ROWS, T1, 0, stream>>>(logits, targets);
    rs_finalize<<<1, 64, 0, stream>>>(targets, draft, bonus, out);
}